// Round 2
// baseline (460.423 us; speedup 1.0000x reference)
//
#include <hip/hip_runtime.h>
#include <stdint.h>

#define B_ROWS 8192
#define DIM 4096
#define E_CODES 512
#define MARGIN 16.0f

typedef __attribute__((ext_vector_type(8))) short short8;
typedef __attribute__((ext_vector_type(4))) float floatx4;
typedef __attribute__((ext_vector_type(4), aligned(4))) float f4u;  // unaligned-ok float4
typedef unsigned short ushort_t;

// ---- workspace layout (float units) ----
#define WS_P0     0                       // partial scores half 0: 8192*512 floats
#define WS_ENORM  4194304                 // 512 floats
#define WS_COUNTS 4194816                 // 512 ints
#define WS_LOSS   4195328                 // 1 float

// ---- output layout (float units) ----
#define O_LOSS 0
#define O_Q    1
#define O_PERP 33554433
#define O_ENC  33554434
// scratch carved out of the Q region (Q is fully overwritten by k_fused afterwards):
#define O_XBF  4          // bf16 X (swizzled): 8192*4096 ushort
#define O_CBBF 20971520   // bf16 CB (swizzled): 512*4096 ushort
// partial scores half 1 lives in the ENC region (read before k_fused overwrites it per-row)

#define AS1 __attribute__((address_space(1)))
#define AS3 __attribute__((address_space(3)))

__device__ __forceinline__ void gld_lds16(const void* g, void* l) {
    // async global->LDS, 16B per lane; LDS dest = wave-uniform base + lane*16
    __builtin_amdgcn_global_load_lds((AS1 const void*)g, (AS3 void*)l, 16, 0, 0);
}

// pack two fp32 into (bf16(hi)<<16)|bf16(lo) by truncation — one v_perm_b32
__device__ inline uint32_t pk2(float hi, float lo) {
    return __builtin_amdgcn_perm(__float_as_uint(hi), __float_as_uint(lo), 0x07060302u);
}

// ---------------- codebook norms (fp32) ----------------
__global__ __launch_bounds__(64) void k_enorm(const float* __restrict__ cb, float* __restrict__ enorm) {
    const int e = blockIdx.x;
    const int lane = threadIdx.x;
    const float4* c4 = (const float4*)(cb + (size_t)e * DIM);
    float p = 0.f;
#pragma unroll
    for (int j = 0; j < 16; j++) {
        float4 v = c4[j * 64 + lane];
        p = fmaf(v.x, v.x, fmaf(v.y, v.y, fmaf(v.z, v.z, fmaf(v.w, v.w, p))));
    }
    for (int off = 32; off; off >>= 1) p += __shfl_down(p, off);
    if (lane == 0) enorm[e] = p;
}

// ---------------- bf16 pack with per-row XOR swizzle ----------------
// Within each 64-elem K-block, 16B-chunk c of row r is stored at chunk (c ^ (r&7)).
// k_gemm stages linearly via global_load_lds; frag ds_reads apply the same XOR.
#define GX_CH (B_ROWS * (DIM / 8))    // 4,194,304 chunks of 8 floats
#define GC_CH (E_CODES * (DIM / 8))   // 262,144
__global__ __launch_bounds__(256) void k_pack(const float* __restrict__ X, const float* __restrict__ CB,
                                              ushort_t* __restrict__ xbf, ushort_t* __restrict__ cbbf) {
    const int stride = gridDim.x * 256;
    for (int idx = blockIdx.x * 256 + threadIdx.x; idx < GX_CH + GC_CH; idx += stride) {
        const float* s;
        ushort_t* dbase;
        int r, g;
        if (idx < GX_CH) {
            r = idx >> 9; g = idx & 511;
            s = X + ((size_t)idx << 3);
            dbase = xbf + (size_t)r * DIM;
        } else {
            const int t = idx - GX_CH;
            r = t >> 9; g = t & 511;
            s = CB + ((size_t)t << 3);
            dbase = cbbf + (size_t)r * DIM;
        }
        const int gs = (g & ~7) | ((g & 7) ^ (r & 7));
        const float4* s4 = (const float4*)s;
        float4 v0 = s4[0], v1 = s4[1];
        *(uint4*)(dbase + gs * 8) =
            make_uint4(pk2(v0.y, v0.x), pk2(v0.w, v0.z), pk2(v1.y, v1.x), pk2(v1.w, v1.z));
    }
}

// ---------------- bf16 score GEMM: BM=64, BN=512 (full N), BK=64, split-K=2 ----------------
// 512 threads = 8 waves, wave w owns cols [w*64, w*64+64), all 64 rows (4x4 frags of 16x16x32).
// grid = 128 bm * 2 kh = 256 blocks -> 1 block/CU. xbf is read exactly once (per kh half);
// cbbf (4 MB) is per-XCD-L2 resident (kh = bid&1 puts one kh half per XCD).
__global__ __launch_bounds__(512, 2) void k_gemm(const ushort_t* __restrict__ xbf, const ushort_t* __restrict__ cbbf,
                                                 const float* __restrict__ enorm,
                                                 float* __restrict__ p0, float* __restrict__ p1) {
    __shared__ __align__(16) ushort_t As[64 * 64];    // 8 KiB
    __shared__ __align__(16) ushort_t Bs[512 * 64];   // 64 KiB
    const int bid = blockIdx.x;
    const int kh = bid & 1;
    const int bm = bid >> 1;
    const int tid = threadIdx.x;
    const int lane = tid & 63;
    const int w = tid >> 6;
    const int m16 = lane & 15, q4 = lane >> 4;

    // staging addresses: lane l covers (row sub = l>>3, 16B chunk = l&7)
    const int srow = lane >> 3;
    const int scol = (lane & 7) * 8;
    const ushort_t* ax = xbf + (size_t)(bm * 64 + w * 8 + srow) * DIM + kh * 2048 + scol;
    const ushort_t* bx = cbbf + (size_t)(w * 8 + srow) * DIM + kh * 2048 + scol;  // + j*64*DIM
    ushort_t* asd = &As[w * 512];
    ushort_t* bsd = &Bs[w * 512];  // + j*4096

    floatx4 acc[4][4];
#pragma unroll
    for (int i = 0; i < 4; i++)
#pragma unroll
        for (int j = 0; j < 4; j++) acc[i][j] = (floatx4){0.f, 0.f, 0.f, 0.f};

    const int kx = (m16 & 7) * 8;  // frag-read XOR key (ushort units)

    for (int kt = 0; kt < 2048; kt += 64) {
        __syncthreads();  // previous step's frag reads complete
        gld_lds16(ax + kt, asd);
#pragma unroll
        for (int j = 0; j < 8; j++) gld_lds16(bx + (size_t)j * 64 * DIM + kt, bsd + j * 4096);
        asm volatile("s_waitcnt vmcnt(0)" ::: "memory");
        __syncthreads();  // staged tile visible

        short8 a[4][2], b[4][2];
#pragma unroll
        for (int i = 0; i < 4; i++)
#pragma unroll
            for (int kk = 0; kk < 2; kk++) {
                a[i][kk] = *(const short8*)(&As[(i * 16 + m16) * 64 + ((kk * 32 + q4 * 8) ^ kx)]);
                b[i][kk] = *(const short8*)(&Bs[(w * 64 + i * 16 + m16) * 64 + ((kk * 32 + q4 * 8) ^ kx)]);
            }
#pragma unroll
        for (int kk = 0; kk < 2; kk++)
#pragma unroll
            for (int i = 0; i < 4; i++)
#pragma unroll
                for (int j = 0; j < 4; j++)
                    acc[i][j] = __builtin_amdgcn_mfma_f32_16x16x32_bf16(a[i][kk], b[j][kk], acc[i][j], 0, 0, 0);
    }

    // epilogue: P0 = ||e||^2 - 2*dot_lo ; P1 = -2*dot_hi ; C/D: col=lane&15, row=(lane>>4)*4+rr
    float* P = kh ? p1 : p0;
#pragma unroll
    for (int j = 0; j < 4; j++) {
        const int col = w * 64 + j * 16 + m16;
        const float en = kh ? 0.f : enorm[col];
#pragma unroll
        for (int i = 0; i < 4; i++) {
            const int row0 = bm * 64 + i * 16 + q4 * 4;
#pragma unroll
            for (int rr = 0; rr < 4; rr++)
                P[(size_t)(row0 + rr) * E_CODES + col] = fmaf(-2.0f, acc[i][j][rr], en);
        }
    }
}

// ---------------- fused: wave-per-row argmin + (rare) exact refine + quantize + one-hot + loss --------
// No register-resident X row (scratch killer); X read from global per use (L1/L2-hot on reuse).
// All array indices compile-time static. p1 aliases the one-hot region (read-before-write per row).
__global__ __launch_bounds__(256) void k_fused(const float* __restrict__ X, const float* __restrict__ CB,
                                               const float* __restrict__ p0, const float* p1,
                                               int* __restrict__ counts, float* __restrict__ loss_sum,
                                               float* out) {
    const int tid = threadIdx.x;
    const int lane = tid & 63, w = tid >> 6;
    const int row = blockIdx.x * 4 + w;

    const float* sr0 = p0 + (size_t)row * E_CODES;
    const float* sr1 = p1 + (size_t)row * E_CODES;
    float s[8];
#pragma unroll
    for (int g = 0; g < 8; g++) s[g] = sr0[g * 64 + lane] + sr1[g * 64 + lane];

    // wave argmin (approx scores), tie -> lower index
    float mv = s[0]; int mi = lane;
#pragma unroll
    for (int g = 1; g < 8; g++) { if (s[g] < mv) { mv = s[g]; mi = g * 64 + lane; } }
    for (int off = 32; off; off >>= 1) {
        float ov = __shfl_xor(mv, off); int oi = __shfl_xor(mi, off);
        if (ov < mv || (ov == mv && oi < mi)) { mv = ov; mi = oi; }
    }
    const float thr = mv + MARGIN;

    // candidate masks (static indexing only)
    unsigned long long m0 = __ballot(s[0] <= thr), m1 = __ballot(s[1] <= thr);
    unsigned long long m2 = __ballot(s[2] <= thr), m3 = __ballot(s[3] <= thr);
    unsigned long long m4 = __ballot(s[4] <= thr), m5 = __ballot(s[5] <= thr);
    unsigned long long m6 = __ballot(s[6] <= thr), m7 = __ballot(s[7] <= thr);
    const int ncand = __popcll(m0) + __popcll(m1) + __popcll(m2) + __popcll(m3) +
                      __popcll(m4) + __popcll(m5) + __popcll(m6) + __popcll(m7);

    const float4* xr4 = (const float4*)(X + (size_t)row * DIM);
    int beste = mi;  // unique candidate == approx argmin

    if (ncand > 1) {
        // exact fp32 refine over margin candidates; butterfly sums bit-identical on all lanes
        float bestd = 3.0e38f; beste = 1 << 30;
#define REFINE_GROUP(MG, G)                                                                 \
        {                                                                                   \
            unsigned long long mask = (MG);                                                 \
            while (mask) {                                                                  \
                const int b = __builtin_ctzll(mask); mask &= mask - 1;                      \
                const int e = (G) * 64 + b;                                                 \
                const float4* cr4 = (const float4*)(CB + (size_t)e * DIM);                  \
                float p = 0.f;                                                              \
                _Pragma("unroll")                                                           \
                for (int i = 0; i < 16; i++) {                                              \
                    float4 c = cr4[i * 64 + lane];                                          \
                    float4 x = xr4[i * 64 + lane];                                          \
                    float dx = x.x - c.x, dy = x.y - c.y, dz = x.z - c.z, dw = x.w - c.w;   \
                    p = fmaf(dx, dx, fmaf(dy, dy, fmaf(dz, dz, fmaf(dw, dw, p))));          \
                }                                                                           \
                for (int off = 32; off; off >>= 1) p += __shfl_xor(p, off);                 \
                if (p < bestd || (p == bestd && e < beste)) { bestd = p; beste = e; }       \
            }                                                                               \
        }
        REFINE_GROUP(m0, 0) REFINE_GROUP(m1, 1) REFINE_GROUP(m2, 2) REFINE_GROUP(m3, 3)
        REFINE_GROUP(m4, 4) REFINE_GROUP(m5, 5) REFINE_GROUP(m6, 6) REFINE_GROUP(m7, 7)
#undef REFINE_GROUP
    }

    // quantized_st = x + (q - x), fp32 semantics of the reference; loss computed here
    // (dx = q-x; squares bitwise equal old (x-c)^2; identical fma nest + butterfly order)
    const float4* cq4 = (const float4*)(CB + (size_t)beste * DIM);
    f4u* oq4 = (f4u*)(out + O_Q + (size_t)row * DIM);   // out+1 is only 4B-aligned
    float p = 0.f;
#pragma unroll
    for (int i = 0; i < 16; i++) {
        float4 x = xr4[i * 64 + lane], q = cq4[i * 64 + lane];
        float dx = q.x - x.x, dy = q.y - x.y, dz = q.z - x.z, dw = q.w - x.w;
        p = fmaf(dx, dx, fmaf(dy, dy, fmaf(dz, dz, fmaf(dw, dw, p))));
        f4u r;
        r.x = x.x + dx; r.y = x.y + dy; r.z = x.z + dz; r.w = x.w + dw;
        oq4[i * 64 + lane] = r;
    }
    for (int off = 32; off; off >>= 1) p += __shfl_xor(p, off);

    // one-hot row (O_ENC is 8B-aligned -> float2); overwrites the p1 row we already consumed
    float2* oe2 = (float2*)(out + O_ENC + (size_t)row * E_CODES);
#pragma unroll
    for (int k = 0; k < 4; k++) {
        const int e0 = (k * 64 + lane) * 2;
        float2 v; v.x = (e0 == beste) ? 1.0f : 0.0f; v.y = (e0 + 1 == beste) ? 1.0f : 0.0f;
        oe2[k * 64 + lane] = v;
    }

    if (lane == 0) {
        atomicAdd(&counts[beste], 1);
        atomicAdd(loss_sum, p);          // p == sum((q-x)^2), exact fp32
    }
}

// ---------------- loss + perplexity ----------------
__global__ __launch_bounds__(512) void k_final(const int* __restrict__ counts, const float* __restrict__ loss_sum,
                                               float* __restrict__ out) {
    const int tid = threadIdx.x;
    const int lane = tid & 63, w = tid >> 6;
    __shared__ float r[8];
    const float p = (float)counts[tid] * (1.0f / 8192.0f);
    float h = p * logf(p + 1e-10f);
    for (int off = 32; off; off >>= 1) h += __shfl_down(h, off);
    if (lane == 0) r[w] = h;
    __syncthreads();
    if (tid == 0) {
        float H = 0.f;
        for (int k = 0; k < 8; k++) H += r[k];
        out[O_PERP] = expf(-H);
        out[O_LOSS] = loss_sum[0] * (1.25f / 33554432.0f);  // q_latent + 0.25*e_latent = 1.25*MSE
    }
}

extern "C" void kernel_launch(void* const* d_in, const int* in_sizes, int n_in,
                              void* d_out, int out_size, void* d_ws, size_t ws_size,
                              hipStream_t stream) {
    const float* X  = (const float*)d_in[0];   // inputs  [8192, 8,8,8,8] -> [8192,4096]
    const float* CB = (const float*)d_in[1];   // codebook [512, 4096]
    float* out = (float*)d_out;
    float* ws  = (float*)d_ws;
    float* p0     = ws + WS_P0;
    float* enorm  = ws + WS_ENORM;
    int*   counts = (int*)(ws + WS_COUNTS);
    float* loss_s = ws + WS_LOSS;
    ushort_t* xbf  = (ushort_t*)(out + O_XBF);
    ushort_t* cbbf = (ushort_t*)(out + O_CBBF);
    float* p1 = out + O_ENC;

    hipMemsetAsync(counts, 0, (E_CODES + 1) * sizeof(int), stream);

    k_pack<<<2048, 256, 0, stream>>>(X, CB, xbf, cbbf);
    k_enorm<<<E_CODES, 64, 0, stream>>>(CB, enorm);
    k_gemm<<<256, 512, 0, stream>>>(xbf, cbbf, enorm, p0, p1);
    k_fused<<<B_ROWS / 4, 256, 0, stream>>>(X, CB, p0, p1, counts, loss_s, out);
    k_final<<<1, 512, 0, stream>>>(counts, loss_s, out);
}